// Round 7
// baseline (370.349 us; speedup 1.0000x reference)
//
#include <hip/hip_runtime.h>

// GraphRec VC_Aggregator — bf16 MFMA, round 6: occupancy fix.
// Changes vs r5: drop fp32 sOf (wsum reads bf16 O from sA3) -> LDS 88.6->54.4KB;
// NB 16->8 -> grid 512 (2 blocks/CU); launch_bounds(512,4) pins VGPR<=128.

#define NB 8
#define NTHR 512

typedef __attribute__((ext_vector_type(8))) short short8;   // 8 bf16 (4 VGPR)
typedef __attribute__((ext_vector_type(4))) float f32x4;

__device__ __forceinline__ float relu_f(float x) { return x > 0.f ? x : 0.f; }

__device__ __forceinline__ short f2bf(float f) {  // RNE float->bf16 bits
  union { float f; unsigned u; } v; v.f = f;
  unsigned r = v.u + 0x7FFFu + ((v.u >> 16) & 1u);
  return (short)(r >> 16);
}

__device__ __forceinline__ float bf2f(short s) {
  union { unsigned u; float f; } v; v.u = ((unsigned)(unsigned short)s) << 16;
  return v.f;
}

__device__ __forceinline__ short8 cvt8(float4 a, float4 b) {
  short8 r;
  r[0] = f2bf(a.x); r[1] = f2bf(a.y); r[2] = f2bf(a.z); r[3] = f2bf(a.w);
  r[4] = f2bf(b.x); r[5] = f2bf(b.y); r[6] = f2bf(b.z); r[7] = f2bf(b.w);
  return r;
}

// Weight B-fragment: lane holds W[d = n0+(lane&15)][k0 + (lane>>4)*8 + e]
__device__ __forceinline__ short8 wfrag(const float* __restrict__ W, int ldk,
                                        int d, int k) {
  const float4* p = (const float4*)(W + (size_t)d * ldk + k);
  return cvt8(p[0], p[1]);
}

// A-fragments from swizzled LDS; acc[mt] over 4 M-tiles (rows mt*16+..).
template <int NS, int ROWB>
__device__ __forceinline__ void run_phase(const char* __restrict__ Abase,
                                          const short8* wf, f32x4 acc[4],
                                          int r16, int kg) {
#pragma unroll
  for (int mt = 0; mt < 4; ++mt) acc[mt] = (f32x4){0.f, 0.f, 0.f, 0.f};
#pragma unroll
  for (int s = 0; s < NS; ++s) {
    const int kb = s * 64 + kg * 16;  // byte offset of this frag's k-start
#pragma unroll
    for (int mt = 0; mt < 4; ++mt) {
      const int row = mt * 16 + r16;
      short8 a = *(const short8*)(Abase + row * ROWB + (kb ^ ((row & 7) << 4)));
      acc[mt] = __builtin_amdgcn_mfma_f32_16x16x32_bf16(a, wf[s], acc[mt], 0, 0, 0);
    }
  }
}

__global__ __launch_bounds__(NTHR, 4)
void vc_agg_kernel(const int* __restrict__ nodes,
                   const int* __restrict__ hvc,
                   const int* __restrict__ hr,
                   const float* __restrict__ c2e,
                   const float* __restrict__ v2e,
                   const float* __restrict__ r2e,
                   const float* __restrict__ w1, const float* __restrict__ b1,
                   const float* __restrict__ w2, const float* __restrict__ b2,
                   const float* __restrict__ a1w, const float* __restrict__ a1b,
                   const float* __restrict__ a2w, const float* __restrict__ a2b,
                   const float* __restrict__ a3w,
                   float* __restrict__ out)
{
  __shared__ __align__(16) char sA3[64 * 512];  // E (p1 A) / [O|u] (p3 A), bf16 swz
  __shared__ __align__(16) char sX[64 * 256];   // X (p2 A) / A1 (p4 A), bf16 swz
  __shared__ float sU[128];
  __shared__ int sIvc[50], sIr[50];
  __shared__ float sPlog[8 * 64];
  __shared__ float sWts[64];
  __shared__ float sPs[4 * 128];

  const int tid = threadIdx.x;
  const int w = tid >> 6;          // wave 0..7 -> N-tile (cols 16w..16w+15)
  const int lane = tid & 63;
  const int r16 = lane & 15;
  const int kg = lane >> 4;        // 0..3
  const int col = w * 16 + r16;    // this lane's output column

  // ---- one-time: register-resident weight fragments (bf16) + scalars ----
  short8 wf1[8], wf2[4], wfa1[8], wfa2[4];
#pragma unroll
  for (int s = 0; s < 8; ++s) wf1[s] = wfrag(w1, 256, col, s * 32 + kg * 8);
#pragma unroll
  for (int s = 0; s < 4; ++s) wf2[s] = wfrag(w2, 128, col, s * 32 + kg * 8);
#pragma unroll
  for (int s = 0; s < 8; ++s) wfa1[s] = wfrag(a1w, 256, col, s * 32 + kg * 8);
#pragma unroll
  for (int s = 0; s < 4; ++s) wfa2[s] = wfrag(a2w, 128, col, s * 32 + kg * 8);
  const float b1v = b1[col], b2v = b2[col];
  const float a1bv = a1b[col], a2bv = a2b[col], a3v = a3w[col];

  const int el = tid >> 3, esub = tid & 7;  // E-stage / u-fill mapping

  for (int ib = 0; ib < NB; ++ib) {
    const int b = blockIdx.x * NB + ib;

    // ---- stage indices + u ----
    if (tid < 50) { sIvc[tid] = hvc[b * 50 + tid]; sIr[tid] = hr[b * 50 + tid]; }
    if (tid < 128) sU[tid] = v2e[(size_t)nodes[b] * 128 + tid];
    __syncthreads();

    // ---- stage E = [c2e|r2e] -> sA3 (bf16, swizzled) ----
    if (el < 50) {
      const int kk = esub * 32;  // 32 k per thread, single table per thread
      const float* src = (kk < 128) ? (c2e + (size_t)sIvc[el] * 128 + kk)
                                    : (r2e + (size_t)sIr[el] * 128 + (kk - 128));
#pragma unroll
      for (int j = 0; j < 4; ++j) {
        const float4* p = (const float4*)(src + j * 8);
        const int kb = (kk + j * 8) * 2;
        *(short8*)(sA3 + el * 512 + (kb ^ ((el & 7) << 4))) = cvt8(p[0], p[1]);
      }
    }
    __syncthreads();

    f32x4 acc[4];

    // ---- phase 1: X = relu(E @ w1^T + b1), K=256 ----
    run_phase<8, 512>(sA3, wf1, acc, r16, kg);
#pragma unroll
    for (int mt = 0; mt < 4; ++mt)
#pragma unroll
      for (int r = 0; r < 4; ++r) {
        const int row = mt * 16 + kg * 4 + r;
        *(short*)(sX + row * 256 + ((col * 2) ^ ((row & 7) << 4))) =
            f2bf(relu_f(acc[mt][r] + b1v));
      }
    __syncthreads();

    // ---- phase 2: O = relu(X @ w2^T + b2), K=128 ----
    run_phase<4, 256>(sX, wf2, acc, r16, kg);
#pragma unroll
    for (int mt = 0; mt < 4; ++mt)
#pragma unroll
      for (int r = 0; r < 4; ++r) {
        const int row = mt * 16 + kg * 4 + r;
        *(short*)(sA3 + row * 512 + ((col * 2) ^ ((row & 7) << 4))) =
            f2bf(relu_f(acc[mt][r] + b2v));
      }
    // ---- fill u into cols 128..255 of sA3 (phase-3 A = [O | u]) ----
    {
      const float* up = sU + esub * 16;
#pragma unroll
      for (int m = 0; m < 2; ++m) {
        const int kb = (128 + esub * 16 + m * 8) * 2;
        *(short8*)(sA3 + el * 512 + (kb ^ ((el & 7) << 4))) =
            cvt8(*(const float4*)(up + m * 8), *(const float4*)(up + m * 8 + 4));
      }
    }
    __syncthreads();

    // ---- phase 3: A1 = relu([O|u] @ a1w^T + a1b), K=256 ----
    run_phase<8, 512>(sA3, wfa1, acc, r16, kg);
#pragma unroll
    for (int mt = 0; mt < 4; ++mt)
#pragma unroll
      for (int r = 0; r < 4; ++r) {
        const int row = mt * 16 + kg * 4 + r;
        *(short*)(sX + row * 256 + ((col * 2) ^ ((row & 7) << 4))) =
            f2bf(relu_f(acc[mt][r] + a1bv));
      }
    __syncthreads();

    // ---- phase 4: logits = relu(A1 @ a2w^T + a2b) . a3w  (fused) ----
    run_phase<4, 256>(sX, wfa2, acc, r16, kg);
    {
      float pm[4][4];
#pragma unroll
      for (int mt = 0; mt < 4; ++mt)
#pragma unroll
        for (int r = 0; r < 4; ++r) {
          float v = relu_f(acc[mt][r] + a2bv) * a3v;
#pragma unroll
          for (int off = 1; off < 16; off <<= 1) v += __shfl_xor(v, off);
          pm[mt][r] = v;  // row-sum over this wave's 16 cols
        }
      if (r16 == 0) {
#pragma unroll
        for (int mt = 0; mt < 4; ++mt)
#pragma unroll
          for (int r = 0; r < 4; ++r)
            sPlog[w * 64 + mt * 16 + kg * 4 + r] = pm[mt][r];
      }
    }
    __syncthreads();

    // ---- reduce logits over waves + softmax over L=50 (wave 0) ----
    if (tid < 64) {
      float s = 0.f;
#pragma unroll
      for (int ww = 0; ww < 8; ++ww) s += sPlog[ww * 64 + tid];
      float x = (tid < 50) ? s : -3.4e38f;
#pragma unroll
      for (int off = 32; off; off >>= 1) x = fmaxf(x, __shfl_xor(x, off));
      const float e = (tid < 50) ? __expf(s - x) : 0.f;
      float t = e;
#pragma unroll
      for (int off = 32; off; off >>= 1) t += __shfl_xor(t, off);
      if (tid < 50) sWts[tid] = e / t;
    }
    __syncthreads();

    // ---- out[b][d] = sum_l wts[l] * O[l][d]  (bf16 O from sA3) ----
    {
      const int d = tid & 127, g = tid >> 7;  // 4 row-groups
      const int lb = g * 13, le = (lb + 13 < 50) ? lb + 13 : 50;
      float s = 0.f;
      for (int l = lb; l < le; ++l) {
        const short ov = *(const short*)(sA3 + l * 512 + ((d * 2) ^ ((l & 7) << 4)));
        s = fmaf(sWts[l], bf2f(ov), s);
      }
      sPs[g * 128 + d] = s;
    }
    __syncthreads();
    if (tid < 128)
      out[(size_t)b * 128 + tid] =
          sPs[tid] + sPs[128 + tid] + sPs[256 + tid] + sPs[384 + tid];
    __syncthreads();
  }
}

extern "C" void kernel_launch(void* const* d_in, const int* in_sizes, int n_in,
                              void* d_out, int out_size, void* d_ws, size_t ws_size,
                              hipStream_t stream) {
  const int* nodes = (const int*)d_in[0];
  const int* hvc   = (const int*)d_in[1];
  const int* hr    = (const int*)d_in[2];
  const float* c2e = (const float*)d_in[3];
  const float* v2e = (const float*)d_in[4];
  const float* r2e = (const float*)d_in[5];
  const float* w1  = (const float*)d_in[6];
  const float* b1  = (const float*)d_in[7];
  const float* w2  = (const float*)d_in[8];
  const float* b2  = (const float*)d_in[9];
  const float* a1w = (const float*)d_in[10];
  const float* a1b = (const float*)d_in[11];
  const float* a2w = (const float*)d_in[12];
  const float* a2b = (const float*)d_in[13];
  const float* a3w = (const float*)d_in[14];
  float* out = (float*)d_out;

  vc_agg_kernel<<<4096 / NB, NTHR, 0, stream>>>(nodes, hvc, hr, c2e, v2e, r2e,
                                                w1, b1, w2, b2, a1w, a1b, a2w,
                                                a2b, a3w, out);
}

// Round 8
// 285.133 us; speedup vs baseline: 1.2989x; 1.2989x over previous
//
#include <hip/hip_runtime.h>

// GraphRec VC_Aggregator — bf16 MFMA, round 8.
// vs r5 (175us best): process TWO b's per phase (M=128 rows), halving
// barriers/b and doubling MFMA ILP (acc[8]); serial epilogues amortized,
// softmax for b0/b1 on two waves concurrently. 1 block/CU by design
// (LDS ~104KB), launch_bounds(512,2) — r7's (512,4) forced VGPR=64 and
// spilled the 96-VGPR weight fragments to scratch (444MB HBM refetch).

#define NB 16      // b's per block (8 iterations x 2)
#define NTHR 512

typedef __attribute__((ext_vector_type(8))) short short8;   // 8 bf16 (4 VGPR)
typedef __attribute__((ext_vector_type(4))) float f32x4;

__device__ __forceinline__ float relu_f(float x) { return x > 0.f ? x : 0.f; }

__device__ __forceinline__ short f2bf(float f) {  // RNE float->bf16 bits
  union { float f; unsigned u; } v; v.f = f;
  unsigned r = v.u + 0x7FFFu + ((v.u >> 16) & 1u);
  return (short)(r >> 16);
}

__device__ __forceinline__ float bf2f(short s) {
  union { unsigned u; float f; } v; v.u = ((unsigned)(unsigned short)s) << 16;
  return v.f;
}

__device__ __forceinline__ short8 cvt8(float4 a, float4 b) {
  short8 r;
  r[0] = f2bf(a.x); r[1] = f2bf(a.y); r[2] = f2bf(a.z); r[3] = f2bf(a.w);
  r[4] = f2bf(b.x); r[5] = f2bf(b.y); r[6] = f2bf(b.z); r[7] = f2bf(b.w);
  return r;
}

// Weight B-fragment: lane holds W[d][k + (lane>>4)*8 + e], d = this lane's col
__device__ __forceinline__ short8 wfrag(const float* __restrict__ W, int ldk,
                                        int d, int k) {
  const float4* p = (const float4*)(W + (size_t)d * ldk + k);
  return cvt8(p[0], p[1]);
}

// A-fragments from swizzled LDS; 8 M-tiles (128 rows = 2 b's).
template <int NS, int ROWB>
__device__ __forceinline__ void run_phase(const char* __restrict__ Abase,
                                          const short8* wf, f32x4 acc[8],
                                          int r16, int kg) {
#pragma unroll
  for (int mt = 0; mt < 8; ++mt) acc[mt] = (f32x4){0.f, 0.f, 0.f, 0.f};
#pragma unroll
  for (int s = 0; s < NS; ++s) {
    const int kb = s * 64 + kg * 16;  // byte offset of this frag's k-start
#pragma unroll
    for (int mt = 0; mt < 8; ++mt) {
      const int row = mt * 16 + r16;
      short8 a = *(const short8*)(Abase + row * ROWB + (kb ^ ((row & 7) << 4)));
      acc[mt] = __builtin_amdgcn_mfma_f32_16x16x32_bf16(a, wf[s], acc[mt], 0, 0, 0);
    }
  }
}

__global__ __launch_bounds__(NTHR, 2)
void vc_agg_kernel(const int* __restrict__ nodes,
                   const int* __restrict__ hvc,
                   const int* __restrict__ hr,
                   const float* __restrict__ c2e,
                   const float* __restrict__ v2e,
                   const float* __restrict__ r2e,
                   const float* __restrict__ w1, const float* __restrict__ b1,
                   const float* __restrict__ w2, const float* __restrict__ b2,
                   const float* __restrict__ a1w, const float* __restrict__ a1b,
                   const float* __restrict__ a2w, const float* __restrict__ a2b,
                   const float* __restrict__ a3w,
                   float* __restrict__ out)
{
  __shared__ __align__(16) char sA3[128 * 512];  // E / [O|u], 2 b's, bf16 swz
  __shared__ __align__(16) char sX[128 * 256];   // X / A1, 2 b's, bf16 swz
  __shared__ float sU[256];                      // u for b0,b1
  __shared__ int sIvc[100], sIr[100];
  __shared__ float sPlog[8 * 128];
  __shared__ float sWts[128];
  __shared__ float sPs[512];

  const int tid = threadIdx.x;
  const int w = tid >> 6;          // wave 0..7 -> N-tile (cols 16w..16w+15)
  const int lane = tid & 63;
  const int r16 = lane & 15;
  const int kg = lane >> 4;        // 0..3
  const int col = w * 16 + r16;    // this lane's output column

  // ---- one-time: register-resident weight fragments (bf16) + scalars ----
  short8 wf1[8], wf2[4], wfa1[8], wfa2[4];
#pragma unroll
  for (int s = 0; s < 8; ++s) wf1[s] = wfrag(w1, 256, col, s * 32 + kg * 8);
#pragma unroll
  for (int s = 0; s < 4; ++s) wf2[s] = wfrag(w2, 128, col, s * 32 + kg * 8);
#pragma unroll
  for (int s = 0; s < 8; ++s) wfa1[s] = wfrag(a1w, 256, col, s * 32 + kg * 8);
#pragma unroll
  for (int s = 0; s < 4; ++s) wfa2[s] = wfrag(a2w, 128, col, s * 32 + kg * 8);
  const float b1v = b1[col], b2v = b2[col];
  const float a1bv = a1b[col], a2bv = a2b[col], a3v = a3w[col];

  const int el = tid >> 2, esub = tid & 3;  // 128 rows x 4 k-quarters

  for (int ib = 0; ib < NB; ib += 2) {
    const int b0 = blockIdx.x * NB + ib;

    // ---- stage indices + u (2 b's; hvc/hr rows are contiguous) ----
    if (tid < 100) { sIvc[tid] = hvc[b0 * 50 + tid]; sIr[tid] = hr[b0 * 50 + tid]; }
    if (tid < 256) sU[tid] = v2e[(size_t)nodes[b0 + (tid >> 7)] * 128 + (tid & 127)];
    __syncthreads();

    // ---- stage E = [c2e|r2e] -> sA3 rows 0..127 (bf16, swizzled) ----
    {
      const int l = el & 63, half = el >> 6;
      if (l < 50) {
        const int kk = esub * 64;  // 64 k per thread, single table per thread
        const float* src = (kk < 128)
            ? (c2e + (size_t)sIvc[half * 50 + l] * 128 + kk)
            : (r2e + (size_t)sIr[half * 50 + l] * 128 + (kk - 128));
#pragma unroll
        for (int j = 0; j < 8; ++j) {
          const float4* p = (const float4*)(src + j * 8);
          const int kb = (kk + j * 8) * 2;
          *(short8*)(sA3 + el * 512 + (kb ^ ((el & 7) << 4))) = cvt8(p[0], p[1]);
        }
      }
    }
    __syncthreads();

    f32x4 acc[8];

    // ---- phase 1: X = relu(E @ w1^T + b1), K=256 ----
    run_phase<8, 512>(sA3, wf1, acc, r16, kg);
#pragma unroll
    for (int mt = 0; mt < 8; ++mt)
#pragma unroll
      for (int r = 0; r < 4; ++r) {
        const int row = mt * 16 + kg * 4 + r;
        *(short*)(sX + row * 256 + ((col * 2) ^ ((row & 7) << 4))) =
            f2bf(relu_f(acc[mt][r] + b1v));
      }
    __syncthreads();

    // ---- phase 2: O = relu(X @ w2^T + b2), K=128 ----
    run_phase<4, 256>(sX, wf2, acc, r16, kg);
#pragma unroll
    for (int mt = 0; mt < 8; ++mt)
#pragma unroll
      for (int r = 0; r < 4; ++r) {
        const int row = mt * 16 + kg * 4 + r;
        *(short*)(sA3 + row * 512 + ((col * 2) ^ ((row & 7) << 4))) =
            f2bf(relu_f(acc[mt][r] + b2v));
      }
    // ---- fill u into cols 128..255 of sA3 (phase-3 A = [O | u]) ----
    {
      const float* up = sU + (el >> 6) * 128 + esub * 32;
#pragma unroll
      for (int m = 0; m < 4; ++m) {
        const int kb = (128 + esub * 32 + m * 8) * 2;
        *(short8*)(sA3 + el * 512 + (kb ^ ((el & 7) << 4))) =
            cvt8(*(const float4*)(up + m * 8), *(const float4*)(up + m * 8 + 4));
      }
    }
    __syncthreads();

    // ---- phase 3: A1 = relu([O|u] @ a1w^T + a1b), K=256 ----
    run_phase<8, 512>(sA3, wfa1, acc, r16, kg);
#pragma unroll
    for (int mt = 0; mt < 8; ++mt)
#pragma unroll
      for (int r = 0; r < 4; ++r) {
        const int row = mt * 16 + kg * 4 + r;
        *(short*)(sX + row * 256 + ((col * 2) ^ ((row & 7) << 4))) =
            f2bf(relu_f(acc[mt][r] + a1bv));
      }
    __syncthreads();

    // ---- phase 4: logits = relu(A1 @ a2w^T + a2b) . a3w  (fused) ----
    run_phase<4, 256>(sX, wfa2, acc, r16, kg);
    {
#pragma unroll
      for (int mt = 0; mt < 8; ++mt) {
        float pv[4];
#pragma unroll
        for (int r = 0; r < 4; ++r) {
          float v = relu_f(acc[mt][r] + a2bv) * a3v;
#pragma unroll
          for (int off = 1; off < 16; off <<= 1) v += __shfl_xor(v, off);
          pv[r] = v;  // row-sum over this wave's 16 cols
        }
        if (r16 == 0) {
#pragma unroll
          for (int r = 0; r < 4; ++r)
            sPlog[w * 128 + mt * 16 + kg * 4 + r] = pv[r];
        }
      }
    }
    __syncthreads();

    // ---- reduce logits over waves + two concurrent softmaxes (L=50) ----
    if (tid < 128) {
      float s = 0.f;
#pragma unroll
      for (int ww = 0; ww < 8; ++ww) s += sPlog[ww * 128 + tid];
      const int l = tid & 63;
      float x = (l < 50) ? s : -3.4e38f;
#pragma unroll
      for (int off = 32; off; off >>= 1) x = fmaxf(x, __shfl_xor(x, off));
      const float e = (l < 50) ? __expf(s - x) : 0.f;
      float t = e;
#pragma unroll
      for (int off = 32; off; off >>= 1) t += __shfl_xor(t, off);
      sWts[tid] = e / t;
    }
    __syncthreads();

    // ---- out[b][d] = sum_l wts[l] * O[l][d]  (bf16 O from sA3) ----
    {
      const int d = tid & 127, bh = (tid >> 7) & 1, g = tid >> 8;  // g: 2 groups
      const int lb = g * 25, le = lb + 25;
      float s = 0.f;
      for (int l = lb; l < le; ++l) {
        const int row = bh * 64 + l;
        const short ov =
            *(const short*)(sA3 + row * 512 + ((d * 2) ^ ((l & 7) << 4)));
        s = fmaf(sWts[bh * 64 + l], bf2f(ov), s);
      }
      sPs[g * 256 + bh * 128 + d] = s;
    }
    __syncthreads();
    if (tid < 256)
      out[(size_t)(b0 + (tid >> 7)) * 128 + (tid & 127)] =
          sPs[tid] + sPs[256 + tid];
    __syncthreads();
  }
}

extern "C" void kernel_launch(void* const* d_in, const int* in_sizes, int n_in,
                              void* d_out, int out_size, void* d_ws, size_t ws_size,
                              hipStream_t stream) {
  const int* nodes = (const int*)d_in[0];
  const int* hvc   = (const int*)d_in[1];
  const int* hr    = (const int*)d_in[2];
  const float* c2e = (const float*)d_in[3];
  const float* v2e = (const float*)d_in[4];
  const float* r2e = (const float*)d_in[5];
  const float* w1  = (const float*)d_in[6];
  const float* b1  = (const float*)d_in[7];
  const float* w2  = (const float*)d_in[8];
  const float* b2  = (const float*)d_in[9];
  const float* a1w = (const float*)d_in[10];
  const float* a1b = (const float*)d_in[11];
  const float* a2w = (const float*)d_in[12];
  const float* a2b = (const float*)d_in[13];
  const float* a3w = (const float*)d_in[14];
  float* out = (float*)d_out;

  vc_agg_kernel<<<4096 / NB, NTHR, 0, stream>>>(nodes, hvc, hr, c2e, v2e, r2e,
                                                w1, b1, w2, b2, a1w, a1b, a2w,
                                                a2b, a3w, out);
}

// Round 11
// 278.562 us; speedup vs baseline: 1.3295x; 1.0236x over previous
//
#include <hip/hip_runtime.h>

// GraphRec VC_Aggregator — bf16 MFMA, round 9: weight streaming for occupancy.
// R8 lesson: acc[8] 2-b variant spilled (WRITE 25MB). R5 lesson: 96 resident
// weight VGPRs + unified AGPR file -> ~150 regs/wave -> only 8 waves/CU.
// This round: pre-kernel converts weights to bf16 frags in d_ws (192KB, L2);
// main kernel streams 4-8 frags per phase (live wf=32 regs) -> total ~100
// regs -> 2 blocks/CU (16 waves). LDS 54.4KB, NB=8 -> grid 512 = 2/CU.

#define NB 8
#define NTHR 512

// d_ws fragment layout (units of 8-short frags): [s][kg][col]
#define WS_W1 0
#define WS_W2 4096
#define WS_A1 6144
#define WS_A2 10240
#define WS_FRAGS 12288   // * 16B = 196608 bytes

typedef __attribute__((ext_vector_type(8))) short short8;   // 8 bf16 (4 VGPR)
typedef __attribute__((ext_vector_type(4))) float f32x4;

__device__ __forceinline__ float relu_f(float x) { return x > 0.f ? x : 0.f; }

__device__ __forceinline__ short f2bf(float f) {  // RNE float->bf16 bits
  union { float f; unsigned u; } v; v.f = f;
  unsigned r = v.u + 0x7FFFu + ((v.u >> 16) & 1u);
  return (short)(r >> 16);
}

__device__ __forceinline__ float bf2f(short s) {
  union { unsigned u; float f; } v; v.u = ((unsigned)(unsigned short)s) << 16;
  return v.f;
}

__device__ __forceinline__ short8 cvt8(float4 a, float4 b) {
  short8 r;
  r[0] = f2bf(a.x); r[1] = f2bf(a.y); r[2] = f2bf(a.z); r[3] = f2bf(a.w);
  r[4] = f2bf(b.x); r[5] = f2bf(b.y); r[6] = f2bf(b.z); r[7] = f2bf(b.w);
  return r;
}

// Weight B-fragment from fp32 (fallback path)
__device__ __forceinline__ short8 wfrag(const float* __restrict__ W, int ldk,
                                        int d, int k) {
  const float4* p = (const float4*)(W + (size_t)d * ldk + k);
  return cvt8(p[0], p[1]);
}

// ---- pre-kernel: convert 4 weight matrices to bf16 frag layout in ws ----
__global__ __launch_bounds__(256)
void conv_weights(const float* __restrict__ w1, const float* __restrict__ w2,
                  const float* __restrict__ a1w, const float* __restrict__ a2w,
                  short* __restrict__ ws) {
  const int id = blockIdx.x * 256 + threadIdx.x;  // 0..12287
  const float* W; int ldk, base;
  if (id < WS_W2)      { W = w1;  ldk = 256; base = WS_W1; }
  else if (id < WS_A1) { W = w2;  ldk = 128; base = WS_W2; }
  else if (id < WS_A2) { W = a1w; ldk = 256; base = WS_A1; }
  else                 { W = a2w; ldk = 128; base = WS_A2; }
  const int local = id - base;
  const int col = local & 127, kg = (local >> 7) & 3, s = local >> 9;
  const float4* p = (const float4*)(W + (size_t)col * ldk + s * 32 + kg * 8);
  *(short8*)(ws + (size_t)id * 8) = cvt8(p[0], p[1]);
}

// A-fragments from swizzled LDS; acc[mt] over 4 M-tiles (rows mt*16+..).
template <int NS, int ROWB>
__device__ __forceinline__ void run_phase(const char* __restrict__ Abase,
                                          const short8* wf, f32x4 acc[4],
                                          int r16, int kg) {
#pragma unroll
  for (int mt = 0; mt < 4; ++mt) acc[mt] = (f32x4){0.f, 0.f, 0.f, 0.f};
#pragma unroll
  for (int s = 0; s < NS; ++s) {
    const int kb = s * 64 + kg * 16;  // byte offset of this frag's k-start
#pragma unroll
    for (int mt = 0; mt < 4; ++mt) {
      const int row = mt * 16 + r16;
      short8 a = *(const short8*)(Abase + row * ROWB + (kb ^ ((row & 7) << 4)));
      acc[mt] = __builtin_amdgcn_mfma_f32_16x16x32_bf16(a, wf[s], acc[mt], 0, 0, 0);
    }
  }
}

__global__ __launch_bounds__(NTHR, 2)
void vc_agg_kernel(const int* __restrict__ nodes,
                   const int* __restrict__ hvc,
                   const int* __restrict__ hr,
                   const float* __restrict__ c2e,
                   const float* __restrict__ v2e,
                   const float* __restrict__ r2e,
                   const float* __restrict__ w1, const float* __restrict__ b1,
                   const float* __restrict__ w2, const float* __restrict__ b2,
                   const float* __restrict__ a1w, const float* __restrict__ a1b,
                   const float* __restrict__ a2w, const float* __restrict__ a2b,
                   const float* __restrict__ a3w,
                   const short* __restrict__ wsf, int usePre,
                   float* __restrict__ out)
{
  __shared__ __align__(16) char sA3[64 * 512];  // E (p1 A) / [O|u] (p3 A), bf16 swz
  __shared__ __align__(16) char sX[64 * 256];   // X (p2 A) / A1 (p4 A), bf16 swz
  __shared__ float sU[128];
  __shared__ int sIvc[50], sIr[50];
  __shared__ float sPlog[8 * 64];
  __shared__ float sWts[64];
  __shared__ float sPs[4 * 128];

  const int tid = threadIdx.x;
  const int w = tid >> 6;          // wave 0..7 -> N-tile (cols 16w..16w+15)
  const int lane = tid & 63;
  const int r16 = lane & 15;
  const int kg = lane >> 4;        // 0..3
  const int col = w * 16 + r16;    // this lane's output column

  const float b1v = b1[col], b2v = b2[col];
  const float a1bv = a1b[col], a2bv = a2b[col], a3v = a3w[col];

  const int el = tid >> 3, esub = tid & 7;  // E-stage / u-fill mapping

  for (int ib = 0; ib < NB; ++ib) {
    const int b = blockIdx.x * NB + ib;

    // ---- stage indices + u ----
    if (tid < 50) { sIvc[tid] = hvc[b * 50 + tid]; sIr[tid] = hr[b * 50 + tid]; }
    if (tid < 128) sU[tid] = v2e[(size_t)nodes[b] * 128 + tid];
    __syncthreads();

    // ---- stage E = [c2e|r2e] -> sA3 (bf16, swizzled) ----
    if (el < 50) {
      const int kk = esub * 32;  // 32 k per thread, single table per thread
      const float* src = (kk < 128) ? (c2e + (size_t)sIvc[el] * 128 + kk)
                                    : (r2e + (size_t)sIr[el] * 128 + (kk - 128));
#pragma unroll
      for (int j = 0; j < 4; ++j) {
        const float4* p = (const float4*)(src + j * 8);
        const int kb = (kk + j * 8) * 2;
        *(short8*)(sA3 + el * 512 + (kb ^ ((el & 7) << 4))) = cvt8(p[0], p[1]);
      }
    }
    __syncthreads();

    f32x4 acc[4];

    // ---- phase 1: X = relu(E @ w1^T + b1), K=256 ----
    {
      short8 wf[8];
      if (usePre) {
#pragma unroll
        for (int s = 0; s < 8; ++s)
          wf[s] = *(const short8*)(wsf + (size_t)(WS_W1 + (s * 4 + kg) * 128 + col) * 8);
      } else {
#pragma unroll
        for (int s = 0; s < 8; ++s) wf[s] = wfrag(w1, 256, col, s * 32 + kg * 8);
      }
      run_phase<8, 512>(sA3, wf, acc, r16, kg);
    }
#pragma unroll
    for (int mt = 0; mt < 4; ++mt)
#pragma unroll
      for (int r = 0; r < 4; ++r) {
        const int row = mt * 16 + kg * 4 + r;
        *(short*)(sX + row * 256 + ((col * 2) ^ ((row & 7) << 4))) =
            f2bf(relu_f(acc[mt][r] + b1v));
      }
    __syncthreads();

    // ---- phase 2: O = relu(X @ w2^T + b2), K=128 ----
    {
      short8 wf[4];
      if (usePre) {
#pragma unroll
        for (int s = 0; s < 4; ++s)
          wf[s] = *(const short8*)(wsf + (size_t)(WS_W2 + (s * 4 + kg) * 128 + col) * 8);
      } else {
#pragma unroll
        for (int s = 0; s < 4; ++s) wf[s] = wfrag(w2, 128, col, s * 32 + kg * 8);
      }
      run_phase<4, 256>(sX, wf, acc, r16, kg);
    }
#pragma unroll
    for (int mt = 0; mt < 4; ++mt)
#pragma unroll
      for (int r = 0; r < 4; ++r) {
        const int row = mt * 16 + kg * 4 + r;
        *(short*)(sA3 + row * 512 + ((col * 2) ^ ((row & 7) << 4))) =
            f2bf(relu_f(acc[mt][r] + b2v));
      }
    // ---- fill u into cols 128..255 of sA3 (phase-3 A = [O | u]) ----
    {
      const float* up = sU + esub * 16;
#pragma unroll
      for (int m = 0; m < 2; ++m) {
        const int kb = (128 + esub * 16 + m * 8) * 2;
        *(short8*)(sA3 + el * 512 + (kb ^ ((el & 7) << 4))) =
            cvt8(*(const float4*)(up + m * 8), *(const float4*)(up + m * 8 + 4));
      }
    }
    __syncthreads();

    // ---- phase 3: A1 = relu([O|u] @ a1w^T + a1b), K=256 ----
    {
      short8 wf[8];
      if (usePre) {
#pragma unroll
        for (int s = 0; s < 8; ++s)
          wf[s] = *(const short8*)(wsf + (size_t)(WS_A1 + (s * 4 + kg) * 128 + col) * 8);
      } else {
#pragma unroll
        for (int s = 0; s < 8; ++s) wf[s] = wfrag(a1w, 256, col, s * 32 + kg * 8);
      }
      run_phase<8, 512>(sA3, wf, acc, r16, kg);
    }
#pragma unroll
    for (int mt = 0; mt < 4; ++mt)
#pragma unroll
      for (int r = 0; r < 4; ++r) {
        const int row = mt * 16 + kg * 4 + r;
        *(short*)(sX + row * 256 + ((col * 2) ^ ((row & 7) << 4))) =
            f2bf(relu_f(acc[mt][r] + a1bv));
      }
    __syncthreads();

    // ---- phase 4: logits = relu(A1 @ a2w^T + a2b) . a3w  (fused) ----
    {
      short8 wf[4];
      if (usePre) {
#pragma unroll
        for (int s = 0; s < 4; ++s)
          wf[s] = *(const short8*)(wsf + (size_t)(WS_A2 + (s * 4 + kg) * 128 + col) * 8);
      } else {
#pragma unroll
        for (int s = 0; s < 4; ++s) wf[s] = wfrag(a2w, 128, col, s * 32 + kg * 8);
      }
      run_phase<4, 256>(sX, wf, acc, r16, kg);
    }
    {
      float pm[4][4];
#pragma unroll
      for (int mt = 0; mt < 4; ++mt)
#pragma unroll
        for (int r = 0; r < 4; ++r) {
          float v = relu_f(acc[mt][r] + a2bv) * a3v;
#pragma unroll
          for (int off = 1; off < 16; off <<= 1) v += __shfl_xor(v, off);
          pm[mt][r] = v;  // row-sum over this wave's 16 cols
        }
      if (r16 == 0) {
#pragma unroll
        for (int mt = 0; mt < 4; ++mt)
#pragma unroll
          for (int r = 0; r < 4; ++r)
            sPlog[w * 64 + mt * 16 + kg * 4 + r] = pm[mt][r];
      }
    }
    __syncthreads();

    // ---- reduce logits over waves + softmax over L=50 (wave 0) ----
    if (tid < 64) {
      float s = 0.f;
#pragma unroll
      for (int ww = 0; ww < 8; ++ww) s += sPlog[ww * 64 + tid];
      float x = (tid < 50) ? s : -3.4e38f;
#pragma unroll
      for (int off = 32; off; off >>= 1) x = fmaxf(x, __shfl_xor(x, off));
      const float e = (tid < 50) ? __expf(s - x) : 0.f;
      float t = e;
#pragma unroll
      for (int off = 32; off; off >>= 1) t += __shfl_xor(t, off);
      if (tid < 50) sWts[tid] = e / t;
    }
    __syncthreads();

    // ---- out[b][d] = sum_l wts[l] * O[l][d]  (bf16 O from sA3) ----
    {
      const int d = tid & 127, g = tid >> 7;  // 4 row-groups
      const int lb = g * 13, le = (lb + 13 < 50) ? lb + 13 : 50;
      float s = 0.f;
      for (int l = lb; l < le; ++l) {
        const short ov = *(const short*)(sA3 + l * 512 + ((d * 2) ^ ((l & 7) << 4)));
        s = fmaf(sWts[l], bf2f(ov), s);
      }
      sPs[g * 128 + d] = s;
    }
    __syncthreads();
    if (tid < 128)
      out[(size_t)b * 128 + tid] =
          sPs[tid] + sPs[128 + tid] + sPs[256 + tid] + sPs[384 + tid];
    __syncthreads();
  }
}

extern "C" void kernel_launch(void* const* d_in, const int* in_sizes, int n_in,
                              void* d_out, int out_size, void* d_ws, size_t ws_size,
                              hipStream_t stream) {
  const int* nodes = (const int*)d_in[0];
  const int* hvc   = (const int*)d_in[1];
  const int* hr    = (const int*)d_in[2];
  const float* c2e = (const float*)d_in[3];
  const float* v2e = (const float*)d_in[4];
  const float* r2e = (const float*)d_in[5];
  const float* w1  = (const float*)d_in[6];
  const float* b1  = (const float*)d_in[7];
  const float* w2  = (const float*)d_in[8];
  const float* b2  = (const float*)d_in[9];
  const float* a1w = (const float*)d_in[10];
  const float* a1b = (const float*)d_in[11];
  const float* a2w = (const float*)d_in[12];
  const float* a2b = (const float*)d_in[13];
  const float* a3w = (const float*)d_in[14];
  float* out = (float*)d_out;

  const int usePre = (ws_size >= (size_t)WS_FRAGS * 16) ? 1 : 0;
  short* wsf = (short*)d_ws;
  if (usePre)
    conv_weights<<<WS_FRAGS / 256, 256, 0, stream>>>(w1, w2, a1w, a2w, wsf);

  vc_agg_kernel<<<4096 / NB, NTHR, 0, stream>>>(nodes, hvc, hr, c2e, v2e, r2e,
                                                w1, b1, w2, b2, a1w, a1b, a2w,
                                                a2b, a3w, wsf, usePre, out);
}